// Round 3
// baseline (344.483 us; speedup 1.0000x reference)
//
#include <hip/hip_runtime.h>

#define LQN 21760
#define LVN 21760
#define BATCH 2
#define CDIM 256
#define HDN 8
#define DDIM 32

typedef __attribute__((ext_vector_type(8))) short short8;
typedef __attribute__((ext_vector_type(4))) float f32x4;
typedef __attribute__((ext_vector_type(2))) float f32x2;

__device__ __forceinline__ unsigned short f2bf(float f) {
  union { float f; unsigned int u; } v; v.f = f;
  unsigned int r = v.u + 0x7fffu + ((v.u >> 16) & 1u);
  return (unsigned short)(r >> 16);
}
__device__ __forceinline__ float bflo(unsigned int u) {
  union { unsigned int u; float f; } v; v.u = u << 16; return v.f;
}
__device__ __forceinline__ float bfhi(unsigned int u) {
  union { unsigned int u; float f; } v; v.u = u & 0xffff0000u; return v.f;
}

template <int IMM>
__device__ __forceinline__ float swzf(float v) {
  return __int_as_float(__builtin_amdgcn_ds_swizzle(__float_as_int(v), IMM));
}

// ---------------- prep: transpose weights to bf16 W^T[n][k] ----------------
__global__ __launch_bounds__(256) void prep_kernel(
    const float* __restrict__ Wval, const float* __restrict__ Woff,
    const float* __restrict__ Wattn, const float* __restrict__ Wout,
    unsigned short* __restrict__ wtval, unsigned short* __restrict__ wtoa,
    unsigned short* __restrict__ wtout) {
  int idx = blockIdx.x * 256 + threadIdx.x;  // 0 .. 98303
  int n = idx >> 8, k = idx & 255;
  if (idx < 65536) {
    wtval[idx] = f2bf(Wval[k * 256 + n]);
    wtout[idx] = f2bf(Wout[k * 256 + n]);
  }
  if (idx < 98304) {
    float v = (n < 256) ? Woff[k * 256 + n] : Wattn[k * 128 + (n - 256)];
    wtoa[idx] = f2bf(v);
  }
}

// ---------------- GEMM: C[M,N] = A[M,256] @ W[256,N] (+epilogue) ------------
template <int MODE>
__global__ __launch_bounds__(256) void gemm_kernel(
    const float* __restrict__ Af32, const unsigned short* __restrict__ Abf,
    const unsigned short* __restrict__ Wt, const float* __restrict__ bias0,
    const float* __restrict__ bias1, const float* __restrict__ resid,
    unsigned short* __restrict__ out_bf, float* __restrict__ out_f32) {
  constexpr int K = 256;
  constexpr int LDSS = 56;  // padded row stride (shorts): 112B, 16B aligned
  __shared__ unsigned short lsA[64 * LDSS];
  __shared__ unsigned short lsB[64 * LDSS];
  const int m0 = blockIdx.x * 64;
  const int n0 = blockIdx.y * 64;
  const int t = threadIdx.x;
  const int w = t >> 6;
  const int l = t & 63;
  const int fr = l & 15;
  const int kk = (l >> 4) * 8;

  f32x4 acc[4];
#pragma unroll
  for (int c = 0; c < 4; ++c) acc[c] = (f32x4){0.f, 0.f, 0.f, 0.f};

  const int srow = t >> 2;
  const int sk = (t & 3) * 8;

  for (int kt = 0; kt < K / 32; ++kt) {
    const int k0 = kt * 32;
    if (MODE == 2) {
      *(uint4*)(lsA + srow * LDSS + sk) =
          *(const uint4*)(Abf + (size_t)(m0 + srow) * K + k0 + sk);
    } else {
      const float* ap = Af32 + (size_t)(m0 + srow) * K + k0 + sk;
      float4 f0 = *(const float4*)(ap);
      float4 f1 = *(const float4*)(ap + 4);
      uint4 pk;
      pk.x = (unsigned)f2bf(f0.x) | ((unsigned)f2bf(f0.y) << 16);
      pk.y = (unsigned)f2bf(f0.z) | ((unsigned)f2bf(f0.w) << 16);
      pk.z = (unsigned)f2bf(f1.x) | ((unsigned)f2bf(f1.y) << 16);
      pk.w = (unsigned)f2bf(f1.z) | ((unsigned)f2bf(f1.w) << 16);
      *(uint4*)(lsA + srow * LDSS + sk) = pk;
    }
    *(uint4*)(lsB + srow * LDSS + sk) =
        *(const uint4*)(Wt + (size_t)(n0 + srow) * K + k0 + sk);
    __syncthreads();
    const short8 a = *(const short8*)(lsA + (w * 16 + fr) * LDSS + kk);
#pragma unroll
    for (int c = 0; c < 4; ++c) {
      const short8 b = *(const short8*)(lsB + (c * 16 + fr) * LDSS + kk);
      acc[c] = __builtin_amdgcn_mfma_f32_16x16x32_bf16(a, b, acc[c], 0, 0, 0);
    }
    __syncthreads();
  }

  const int fq = l >> 4;
#pragma unroll
  for (int c = 0; c < 4; ++c) {
#pragma unroll
    for (int r = 0; r < 4; ++r) {
      const int row = m0 + w * 16 + fq * 4 + r;
      const int col = n0 + c * 16 + fr;
      float v = acc[c][r];
      if (MODE == 0) {
        v += bias0[col];
        const int bb = (row >= LVN) ? 1 : 0;
        const int i = row - bb * LVN;
        const int h = col >> 5, d = col & 31;
        out_bf[(((size_t)(bb * HDN + h) * LVN + i) << 5) + d] = f2bf(v);
      } else if (MODE == 1) {
        const float bias = (col < 256) ? bias0[col] : bias1[col - 256];
        out_bf[(size_t)row * 384 + col] = f2bf(v + bias);
      } else {
        const size_t o = (size_t)row * 256 + col;
        out_f32[o] = v + bias0[col] + resid[o];
      }
    }
  }
}

// --------- sampler: 2 q/wave; 4 lanes/head; lane j owns level j fully ------
__device__ __forceinline__ void corner_accum(const unsigned short* vhead,
                                             unsigned a, float w, f32x2* acc) {
  const uint4* bp = (const uint4*)(vhead + a);
  const uint4 q0 = bp[0], q1 = bp[1], q2 = bp[2], q3 = bp[3];
  const unsigned u[16] = {q0.x, q0.y, q0.z, q0.w, q1.x, q1.y, q1.z, q1.w,
                          q2.x, q2.y, q2.z, q2.w, q3.x, q3.y, q3.z, q3.w};
#pragma unroll
  for (int k = 0; k < 16; ++k) {
    f32x2 v;
    v.x = bflo(u[k]);
    v.y = bfhi(u[k]);
    acc[k] += v * w;
  }
}

__global__ __launch_bounds__(256, 4) void sampler_kernel(
    const unsigned short* __restrict__ vbf,      // [B,HD,LV,32] bf16
    const unsigned short* __restrict__ offattn,  // [B*LQ,384] bf16
    const float* __restrict__ refpts,            // [B,LQ,4,2] f32
    unsigned short* __restrict__ msout) {        // [B*LQ,256] bf16
  const int t = threadIdx.x;
  const int lane = t & 63;
  const int qi = blockIdx.x * 8 + (t >> 6) * 2 + (lane >> 5);
  const int l5 = lane & 31;
  const int h = l5 >> 2;
  const int j = l5 & 3;  // this lane owns level j (and output dims [8j,8j+8))
  const int bb = (qi >= LQN) ? 1 : 0;

  const unsigned short* oa = offattn + (size_t)qi * 384;

  // ---- distributed softmax: lane j handles logits [4j, 4j+4) ----
  float e0, e1, e2, e3;
  {
    const uint2 lr = *(const uint2*)(oa + 256 + h * 16 + j * 4);
    const float l0 = bflo(lr.x), l1 = bfhi(lr.x);
    const float l2 = bflo(lr.y), l3 = bfhi(lr.y);
    float mx = fmaxf(fmaxf(l0, l1), fmaxf(l2, l3));
    mx = fmaxf(mx, swzf<0x041F>(mx));  // xor 1 within quad
    mx = fmaxf(mx, swzf<0x081F>(mx));  // xor 2 within quad
    e0 = __expf(l0 - mx);
    e1 = __expf(l1 - mx);
    e2 = __expf(l2 - mx);
    e3 = __expf(l3 - mx);
    float s = (e0 + e1) + (e2 + e3);
    s += swzf<0x041F>(s);
    s += swzf<0x081F>(s);
    const float inv = 1.f / s;
    e0 *= inv; e1 *= inv; e2 *= inv; e3 *= inv;
  }
  const float ee[4] = {e0, e1, e2, e3};

  // ---- level geometry for this lane ----
  const int Wl = 128 >> j;
  const int lw = 7 - j;
  const int st = j ? ((j == 1) ? 16384 : ((j == 2) ? 20480 : 21504)) : 0;
  const float fw = (float)Wl;

  const float2 rf = *(const float2*)(refpts + (size_t)qi * 8 + j * 2);
  const uint4 ov = *(const uint4*)(oa + h * 32 + j * 8);
  const unsigned op_[4] = {ov.x, ov.y, ov.z, ov.w};

  const unsigned short* vhead = vbf + (size_t)(bb * HDN + h) * (LVN * DDIM);

  f32x2 acc[16];
#pragma unroll
  for (int k = 0; k < 16; ++k) acc[k] = (f32x2){0.f, 0.f};

#pragma unroll
  for (int p = 0; p < 4; ++p) {
    const float ox = bflo(op_[p]);
    const float oy = bfhi(op_[p]);
    const float xs = fmaf(rf.x, fw, ox) - 0.5f;
    const float ys = fmaf(rf.y, fw, oy) - 0.5f;
    const float x0f = floorf(xs), y0f = floorf(ys);
    const float lx = xs - x0f, ly = ys - y0f;
    const int x0 = (int)x0f, y0 = (int)y0f;
    const float aw = ee[p];
    const float wy1 = aw * ly, wy0 = aw - wy1;
    float w00 = wy0 - wy0 * lx, w01 = wy0 * lx;
    float w10 = wy1 - wy1 * lx, w11 = wy1 * lx;
    const bool vx0 = (unsigned)x0 < (unsigned)Wl;
    const bool vx1 = (unsigned)(x0 + 1) < (unsigned)Wl;
    const bool vy0 = (unsigned)y0 < (unsigned)Wl;
    const bool vy1 = (unsigned)(y0 + 1) < (unsigned)Wl;
    w00 = (vy0 && vx0) ? w00 : 0.f;
    w01 = (vy0 && vx1) ? w01 : 0.f;
    w10 = (vy1 && vx0) ? w10 : 0.f;
    w11 = (vy1 && vx1) ? w11 : 0.f;
    const int x0c = min(max(x0, 0), Wl - 1);
    const int x1c = min(max(x0 + 1, 0), Wl - 1);
    const int y0c = min(max(y0, 0), Wl - 1);
    const int y1c = min(max(y0 + 1, 0), Wl - 1);
    const unsigned r0 = (unsigned)(st + (y0c << lw));
    const unsigned r1 = (unsigned)(st + (y1c << lw));
    corner_accum(vhead, (r0 + x0c) << 5, w00, acc);
    corner_accum(vhead, (r0 + x1c) << 5, w01, acc);
    corner_accum(vhead, (r1 + x0c) << 5, w10, acc);
    corner_accum(vhead, (r1 + x1c) << 5, w11, acc);
  }

  // ---- quad reduce-scatter: lane j ends with pairs [4j,4j+4) in acc[0..3] --
  const bool hi1 = (j & 2) != 0;
#pragma unroll
  for (int k = 0; k < 8; ++k) {
    const f32x2 send = hi1 ? acc[k] : acc[k + 8];
    const f32x2 keep = hi1 ? acc[k + 8] : acc[k];
    f32x2 recv;
    recv.x = swzf<0x081F>(send.x);
    recv.y = swzf<0x081F>(send.y);
    acc[k] = keep + recv;
  }
  const bool hi0 = (j & 1) != 0;
#pragma unroll
  for (int k = 0; k < 4; ++k) {
    const f32x2 send = hi0 ? acc[k] : acc[k + 4];
    const f32x2 keep = hi0 ? acc[k + 4] : acc[k];
    f32x2 recv;
    recv.x = swzf<0x041F>(send.x);
    recv.y = swzf<0x041F>(send.y);
    acc[k] = keep + recv;
  }

  uint4 outv;
  outv.x = (unsigned)f2bf(acc[0].x) | ((unsigned)f2bf(acc[0].y) << 16);
  outv.y = (unsigned)f2bf(acc[1].x) | ((unsigned)f2bf(acc[1].y) << 16);
  outv.z = (unsigned)f2bf(acc[2].x) | ((unsigned)f2bf(acc[2].y) << 16);
  outv.w = (unsigned)f2bf(acc[3].x) | ((unsigned)f2bf(acc[3].y) << 16);
  *(uint4*)(msout + (size_t)qi * 256 + h * 32 + j * 8) = outv;
}

// ---------------- launch ----------------------------------------------------
extern "C" void kernel_launch(void* const* d_in, const int* in_sizes, int n_in,
                              void* d_out, int out_size, void* d_ws,
                              size_t ws_size, hipStream_t stream) {
  const float* query = (const float*)d_in[0];
  const float* refpts = (const float*)d_in[1];
  const float* value = (const float*)d_in[2];
  const float* W_off = (const float*)d_in[5];
  const float* b_off = (const float*)d_in[6];
  const float* W_attn = (const float*)d_in[7];
  const float* b_attn = (const float*)d_in[8];
  const float* W_val = (const float*)d_in[9];
  const float* b_val = (const float*)d_in[10];
  const float* W_out = (const float*)d_in[11];
  const float* b_out = (const float*)d_in[12];
  float* out = (float*)d_out;

  char* ws = (char*)d_ws;
  unsigned short* wtval = (unsigned short*)(ws);                 // 256x256 bf16
  unsigned short* wtoa = (unsigned short*)(ws + 131072);         // 384x256 bf16
  unsigned short* wtout = (unsigned short*)(ws + 327680);        // 256x256 bf16
  unsigned short* vbf = (unsigned short*)(ws + 458752);          // 22282240 B
  unsigned short* offattn = (unsigned short*)(ws + 22740992);    // 33423360 B
  unsigned short* msout = (unsigned short*)(ws + 56164352);      // 22282240 B

  prep_kernel<<<384, 256, 0, stream>>>(W_val, W_off, W_attn, W_out, wtval, wtoa,
                                       wtout);
  gemm_kernel<0><<<dim3(680, 4), 256, 0, stream>>>(
      value, nullptr, wtval, b_val, nullptr, nullptr, vbf, nullptr);
  gemm_kernel<1><<<dim3(680, 6), 256, 0, stream>>>(
      query, nullptr, wtoa, b_off, b_attn, nullptr, offattn, nullptr);
  sampler_kernel<<<5440, 256, 0, stream>>>(vbf, offattn, refpts, msout);
  gemm_kernel<2><<<dim3(680, 4), 256, 0, stream>>>(
      nullptr, msout, wtout, b_out, nullptr, query, nullptr, out);
}

// Round 4
// 205.134 us; speedup vs baseline: 1.6793x; 1.6793x over previous
//
#include <hip/hip_runtime.h>

#define LQN 21760
#define LVN 21760
#define BATCH 2
#define CDIM 256
#define HDN 8
#define DDIM 32
// padded per-(b,h) image: 130*130 + 66*66 + 34*34 + 18*18 = 22736 cells
#define PADCELLS 22736

typedef __attribute__((ext_vector_type(8))) short short8;
typedef __attribute__((ext_vector_type(4))) float f32x4;
typedef __attribute__((ext_vector_type(2))) float f32x2;

__device__ __forceinline__ unsigned short f2bf(float f) {
  union { float f; unsigned int u; } v; v.f = f;
  unsigned int r = v.u + 0x7fffu + ((v.u >> 16) & 1u);
  return (unsigned short)(r >> 16);
}
__device__ __forceinline__ float bflo(unsigned int u) {
  union { unsigned int u; float f; } v; v.u = u << 16; return v.f;
}
__device__ __forceinline__ float bfhi(unsigned int u) {
  union { unsigned int u; float f; } v; v.u = u & 0xffff0000u; return v.f;
}

// ---------------- zero the padded value buffer ------------------------------
__global__ __launch_bounds__(256) void zero_kernel(uint4* __restrict__ p) {
  const int i = blockIdx.x * 256 + threadIdx.x;
  p[i] = (uint4){0u, 0u, 0u, 0u};
}

// ---------------- prep: transpose weights to bf16 W^T[n][k] ----------------
__global__ __launch_bounds__(256) void prep_kernel(
    const float* __restrict__ Wval, const float* __restrict__ Woff,
    const float* __restrict__ Wattn, const float* __restrict__ Wout,
    unsigned short* __restrict__ wtval, unsigned short* __restrict__ wtoa,
    unsigned short* __restrict__ wtout) {
  int idx = blockIdx.x * 256 + threadIdx.x;  // 0 .. 98303
  int n = idx >> 8, k = idx & 255;
  if (idx < 65536) {
    wtval[idx] = f2bf(Wval[k * 256 + n]);
    wtout[idx] = f2bf(Wout[k * 256 + n]);
  }
  if (idx < 98304) {
    float v = (n < 256) ? Woff[k * 256 + n] : Wattn[k * 128 + (n - 256)];
    wtoa[idx] = f2bf(v);
  }
}

// ---------------- GEMM: C[M,N] = A[M,256] @ W[256,N] (+epilogue) ------------
// MODE 0: A=value(f32) -> padded v_bf16[B,HD,PADCELLS,32] scatter (+b_val)
// MODE 1: A=query(f32) -> offattn bf16 [M,384] (+b_off/b_attn)
// MODE 2: A=msout(bf16) -> d_out f32 [M,256] (+b_out +query residual)
template <int MODE>
__global__ __launch_bounds__(256) void gemm_kernel(
    const float* __restrict__ Af32, const unsigned short* __restrict__ Abf,
    const unsigned short* __restrict__ Wt, const float* __restrict__ bias0,
    const float* __restrict__ bias1, const float* __restrict__ resid,
    unsigned short* __restrict__ out_bf, float* __restrict__ out_f32) {
  constexpr int K = 256;
  constexpr int LDSS = 56;  // padded row stride (shorts): 112B, 16B aligned
  __shared__ unsigned short lsA[64 * LDSS];
  __shared__ unsigned short lsB[64 * LDSS];
  const int m0 = blockIdx.x * 64;
  const int n0 = blockIdx.y * 64;
  const int t = threadIdx.x;
  const int w = t >> 6;
  const int l = t & 63;
  const int fr = l & 15;
  const int kk = (l >> 4) * 8;

  f32x4 acc[4];
#pragma unroll
  for (int c = 0; c < 4; ++c) acc[c] = (f32x4){0.f, 0.f, 0.f, 0.f};

  const int srow = t >> 2;
  const int sk = (t & 3) * 8;

  for (int kt = 0; kt < K / 32; ++kt) {
    const int k0 = kt * 32;
    if (MODE == 2) {
      *(uint4*)(lsA + srow * LDSS + sk) =
          *(const uint4*)(Abf + (size_t)(m0 + srow) * K + k0 + sk);
    } else {
      const float* ap = Af32 + (size_t)(m0 + srow) * K + k0 + sk;
      float4 f0 = *(const float4*)(ap);
      float4 f1 = *(const float4*)(ap + 4);
      uint4 pk;
      pk.x = (unsigned)f2bf(f0.x) | ((unsigned)f2bf(f0.y) << 16);
      pk.y = (unsigned)f2bf(f0.z) | ((unsigned)f2bf(f0.w) << 16);
      pk.z = (unsigned)f2bf(f1.x) | ((unsigned)f2bf(f1.y) << 16);
      pk.w = (unsigned)f2bf(f1.z) | ((unsigned)f2bf(f1.w) << 16);
      *(uint4*)(lsA + srow * LDSS + sk) = pk;
    }
    *(uint4*)(lsB + srow * LDSS + sk) =
        *(const uint4*)(Wt + (size_t)(n0 + srow) * K + k0 + sk);
    __syncthreads();
    const short8 a = *(const short8*)(lsA + (w * 16 + fr) * LDSS + kk);
#pragma unroll
    for (int c = 0; c < 4; ++c) {
      const short8 b = *(const short8*)(lsB + (c * 16 + fr) * LDSS + kk);
      acc[c] = __builtin_amdgcn_mfma_f32_16x16x32_bf16(a, b, acc[c], 0, 0, 0);
    }
    __syncthreads();
  }

  const int fq = l >> 4;
#pragma unroll
  for (int c = 0; c < 4; ++c) {
#pragma unroll
    for (int r = 0; r < 4; ++r) {
      const int row = m0 + w * 16 + fq * 4 + r;
      const int col = n0 + c * 16 + fr;
      float v = acc[c][r];
      if (MODE == 0) {
        v += bias0[col];
        const int bb = (row >= LVN) ? 1 : 0;
        const int i = row - bb * LVN;
        const int lvl = (i >= 16384) + (i >= 20480) + (i >= 21504);
        const int stl = (lvl == 0) ? 0 : (lvl == 1) ? 16384 : (lvl == 2) ? 20480 : 21504;
        const int pst = (lvl == 0) ? 0 : (lvl == 1) ? 16900 : (lvl == 2) ? 21256 : 22412;
        const int lw = 7 - lvl;
        const int Wl = 128 >> lvl;
        const int loc = i - stl;
        const int y = loc >> lw;
        const int x = loc & (Wl - 1);
        const int pidx = pst + (y + 1) * (Wl + 2) + (x + 1);
        const int hh = col >> 5, d = col & 31;
        out_bf[(((size_t)(bb * HDN + hh) * PADCELLS + pidx) << 5) + d] = f2bf(v);
      } else if (MODE == 1) {
        const float bias = (col < 256) ? bias0[col] : bias1[col - 256];
        out_bf[(size_t)row * 384 + col] = f2bf(v + bias);
      } else {
        const size_t o = (size_t)row * 256 + col;
        out_f32[o] = v + bias0[col] + resid[o];
      }
    }
  }
}

// -------- sampler: 2 queries/wave; 4 lanes/head, 8 dims/lane; padded v -----
__global__ __launch_bounds__(256) void sampler_kernel(
    const unsigned short* __restrict__ vbf,      // padded [B,HD,PADCELLS,32]
    const unsigned short* __restrict__ offattn,  // [B*LQ,384] bf16
    const float* __restrict__ refpts,            // [B,LQ,4,2] f32
    unsigned short* __restrict__ msout) {        // [B*LQ,256] bf16
  const int t = threadIdx.x;
  const int lane = t & 63;
  const int qi = blockIdx.x * 8 + (t >> 6) * 2 + (lane >> 5);
  const int l5 = lane & 31;
  const int h = l5 >> 2;
  const int d0 = (l5 & 3) * 8;
  const int bb = (qi >= LQN) ? 1 : 0;

  const unsigned short* oa = offattn + (size_t)qi * 384;

  // ---- softmax over 16 logits for this (q,h); fold 1/sum in ----
  float lg[16];
  {
    const uint4 r0 = *(const uint4*)(oa + 256 + h * 16);
    const uint4 r1 = *(const uint4*)(oa + 256 + h * 16 + 8);
    const unsigned int ww[8] = {r0.x, r0.y, r0.z, r0.w, r1.x, r1.y, r1.z, r1.w};
#pragma unroll
    for (int j = 0; j < 8; ++j) {
      lg[2 * j] = bflo(ww[j]);
      lg[2 * j + 1] = bfhi(ww[j]);
    }
  }
  float mx = lg[0];
#pragma unroll
  for (int j = 1; j < 16; ++j) mx = fmaxf(mx, lg[j]);
  float ssum = 0.f;
#pragma unroll
  for (int j = 0; j < 16; ++j) {
    lg[j] = __expf(lg[j] - mx);
    ssum += lg[j];
  }
  const float inv = 1.f / ssum;
#pragma unroll
  for (int j = 0; j < 16; ++j) lg[j] *= inv;

  // lane-constant 32-bit element offset into padded vbf
  const unsigned int headbase =
      (unsigned int)(bb * HDN + h) * (PADCELLS * DDIM) + (unsigned int)d0;

  f32x2 acc0 = (f32x2){0.f, 0.f}, acc1 = (f32x2){0.f, 0.f};
  f32x2 acc2 = (f32x2){0.f, 0.f}, acc3 = (f32x2){0.f, 0.f};

  const float4 refA = *(const float4*)(refpts + (size_t)qi * 8);
  const float4 refB = *(const float4*)(refpts + (size_t)qi * 8 + 4);
  const float rxs[4] = {refA.x, refA.z, refB.x, refB.z};
  const float rys[4] = {refA.y, refA.w, refB.y, refB.w};

#pragma unroll
  for (int lvl = 0; lvl < 4; ++lvl) {
    const int Wl = 128 >> lvl;
    const int W2 = Wl + 2;
    const int pst =
        (lvl == 0) ? 0 : (lvl == 1) ? 16900 : (lvl == 2) ? 21256 : 22412;
    const float fw = (float)Wl;
    const float rx = rxs[lvl], ry = rys[lvl];
    const uint4 ov = *(const uint4*)(oa + h * 32 + lvl * 8);
    const unsigned int op_[4] = {ov.x, ov.y, ov.z, ov.w};
#pragma unroll
    for (int p = 0; p < 4; ++p) {
      const float ox = bflo(op_[p]);
      const float oy = bfhi(op_[p]);
      const float xs = fmaf(rx, fw, ox) - 0.5f;
      const float ys = fmaf(ry, fw, oy) - 0.5f;
      const float x0f = floorf(xs), y0f = floorf(ys);
      const float lx = xs - x0f, ly = ys - y0f;
      const int x0 = (int)x0f, y0 = (int)y0f;
      const float aw = lg[lvl * 4 + p];
      const float wy1 = aw * ly, wy0 = aw - wy1;
      const float w01 = wy0 * lx, w00 = wy0 - w01;
      const float w11 = wy1 * lx, w10 = wy1 - w11;
      // clamp into padded coords (border cells are zero -> OOB contributes 0)
      const int xb0 = min(max(x0 + 1, 0), Wl + 1);
      const int xb1 = min(max(x0 + 2, 0), Wl + 1);
      const int yb0 = min(max(y0 + 1, 0), Wl + 1);
      const int yb1 = min(max(y0 + 2, 0), Wl + 1);
      const unsigned r0 = (unsigned)(pst + yb0 * W2);
      const unsigned r1 = (unsigned)(pst + yb1 * W2);
      const uint4 v00 = *(const uint4*)(vbf + headbase + ((r0 + xb0) << 5));
      const uint4 v01 = *(const uint4*)(vbf + headbase + ((r0 + xb1) << 5));
      const uint4 v10 = *(const uint4*)(vbf + headbase + ((r1 + xb0) << 5));
      const uint4 v11 = *(const uint4*)(vbf + headbase + ((r1 + xb1) << 5));

#define ACCUM(rv, wgt)                                 \
  {                                                    \
    f32x2 v_;                                          \
    v_.x = bflo(rv.x); v_.y = bfhi(rv.x);              \
    acc0 += v_ * (wgt);                                \
    v_.x = bflo(rv.y); v_.y = bfhi(rv.y);              \
    acc1 += v_ * (wgt);                                \
    v_.x = bflo(rv.z); v_.y = bfhi(rv.z);              \
    acc2 += v_ * (wgt);                                \
    v_.x = bflo(rv.w); v_.y = bfhi(rv.w);              \
    acc3 += v_ * (wgt);                                \
  }

      ACCUM(v00, w00)
      ACCUM(v01, w01)
      ACCUM(v10, w10)
      ACCUM(v11, w11)
#undef ACCUM
    }
  }

  uint4 outv;
  outv.x = (unsigned)f2bf(acc0.x) | ((unsigned)f2bf(acc0.y) << 16);
  outv.y = (unsigned)f2bf(acc1.x) | ((unsigned)f2bf(acc1.y) << 16);
  outv.z = (unsigned)f2bf(acc2.x) | ((unsigned)f2bf(acc2.y) << 16);
  outv.w = (unsigned)f2bf(acc3.x) | ((unsigned)f2bf(acc3.y) << 16);
  *(uint4*)(msout + (size_t)qi * 256 + h * 32 + d0) = outv;
}

// ---------------- launch ----------------------------------------------------
extern "C" void kernel_launch(void* const* d_in, const int* in_sizes, int n_in,
                              void* d_out, int out_size, void* d_ws,
                              size_t ws_size, hipStream_t stream) {
  const float* query = (const float*)d_in[0];
  const float* refpts = (const float*)d_in[1];
  const float* value = (const float*)d_in[2];
  const float* W_off = (const float*)d_in[5];
  const float* b_off = (const float*)d_in[6];
  const float* W_attn = (const float*)d_in[7];
  const float* b_attn = (const float*)d_in[8];
  const float* W_val = (const float*)d_in[9];
  const float* b_val = (const float*)d_in[10];
  const float* W_out = (const float*)d_in[11];
  const float* b_out = (const float*)d_in[12];
  float* out = (float*)d_out;

  char* ws = (char*)d_ws;
  unsigned short* wtval = (unsigned short*)(ws);                 // 131072 B
  unsigned short* wtoa = (unsigned short*)(ws + 131072);         // 196608 B
  unsigned short* wtout = (unsigned short*)(ws + 327680);        // 131072 B
  unsigned short* vbf = (unsigned short*)(ws + 458752);          // 23281664 B
  unsigned short* offattn = (unsigned short*)(ws + 23740416);    // 33423360 B
  unsigned short* msout = (unsigned short*)(ws + 57163776);      // 22282240 B

  // 2*8*PADCELLS*32 shorts = 1455104 uint4
  zero_kernel<<<5684, 256, 0, stream>>>((uint4*)vbf);
  prep_kernel<<<384, 256, 0, stream>>>(W_val, W_off, W_attn, W_out, wtval, wtoa,
                                       wtout);
  gemm_kernel<0><<<dim3(680, 4), 256, 0, stream>>>(
      value, nullptr, wtval, b_val, nullptr, nullptr, vbf, nullptr);
  gemm_kernel<1><<<dim3(680, 6), 256, 0, stream>>>(
      query, nullptr, wtoa, b_off, b_attn, nullptr, offattn, nullptr);
  sampler_kernel<<<5440, 256, 0, stream>>>(vbf, offattn, refpts, msout);
  gemm_kernel<2><<<dim3(680, 4), 256, 0, stream>>>(
      nullptr, msout, wtout, b_out, nullptr, query, nullptr, out);
}

// Round 5
// 186.237 us; speedup vs baseline: 1.8497x; 1.1015x over previous
//
#include <hip/hip_runtime.h>

#define LQN 21760
#define LVN 21760
#define BATCH 2
#define CDIM 256
#define HDN 8
#define DDIM 32
// padded per-(b,h) image: 130*130 + 66*66 + 34*34 + 18*18 = 22736 cells
#define PADCELLS 22736

typedef __attribute__((ext_vector_type(8))) short short8;
typedef __attribute__((ext_vector_type(4))) float f32x4;
typedef __attribute__((ext_vector_type(2))) float f32x2;

__device__ __forceinline__ unsigned short f2bf(float f) {
  union { float f; unsigned int u; } v; v.f = f;
  unsigned int r = v.u + 0x7fffu + ((v.u >> 16) & 1u);
  return (unsigned short)(r >> 16);
}
__device__ __forceinline__ float bflo(unsigned int u) {
  union { unsigned int u; float f; } v; v.u = u << 16; return v.f;
}
__device__ __forceinline__ float bfhi(unsigned int u) {
  union { unsigned int u; float f; } v; v.u = u & 0xffff0000u; return v.f;
}

// ---------------- zero the padded value buffer ------------------------------
__global__ __launch_bounds__(256) void zero_kernel(uint4* __restrict__ p) {
  const int i = blockIdx.x * 256 + threadIdx.x;
  p[i] = (uint4){0u, 0u, 0u, 0u};
}

// ---------------- prep: transpose weights to bf16 W^T[n][k] ----------------
__global__ __launch_bounds__(256) void prep_kernel(
    const float* __restrict__ Wval, const float* __restrict__ Woff,
    const float* __restrict__ Wattn, const float* __restrict__ Wout,
    unsigned short* __restrict__ wtval, unsigned short* __restrict__ wtoa,
    unsigned short* __restrict__ wtout) {
  int idx = blockIdx.x * 256 + threadIdx.x;  // 0 .. 98303
  int n = idx >> 8, k = idx & 255;
  if (idx < 65536) {
    wtval[idx] = f2bf(Wval[k * 256 + n]);
    wtout[idx] = f2bf(Wout[k * 256 + n]);
  }
  if (idx < 98304) {
    float v = (n < 256) ? Woff[k * 256 + n] : Wattn[k * 128 + (n - 256)];
    wtoa[idx] = f2bf(v);
  }
}

// ---------------- GEMM: C[M,N] = A[M,256] @ W[256,N] (+epilogue) ------------
template <int MODE>
__global__ __launch_bounds__(256) void gemm_kernel(
    const float* __restrict__ Af32, const unsigned short* __restrict__ Abf,
    const unsigned short* __restrict__ Wt, const float* __restrict__ bias0,
    const float* __restrict__ bias1, const float* __restrict__ resid,
    unsigned short* __restrict__ out_bf, float* __restrict__ out_f32) {
  constexpr int K = 256;
  constexpr int LDSS = 56;  // padded row stride (shorts): 112B, 16B aligned
  __shared__ unsigned short lsA[64 * LDSS];
  __shared__ unsigned short lsB[64 * LDSS];
  const int m0 = blockIdx.x * 64;
  const int n0 = blockIdx.y * 64;
  const int t = threadIdx.x;
  const int w = t >> 6;
  const int l = t & 63;
  const int fr = l & 15;
  const int kk = (l >> 4) * 8;

  f32x4 acc[4];
#pragma unroll
  for (int c = 0; c < 4; ++c) acc[c] = (f32x4){0.f, 0.f, 0.f, 0.f};

  const int srow = t >> 2;
  const int sk = (t & 3) * 8;

  for (int kt = 0; kt < K / 32; ++kt) {
    const int k0 = kt * 32;
    if (MODE == 2) {
      *(uint4*)(lsA + srow * LDSS + sk) =
          *(const uint4*)(Abf + (size_t)(m0 + srow) * K + k0 + sk);
    } else {
      const float* ap = Af32 + (size_t)(m0 + srow) * K + k0 + sk;
      float4 f0 = *(const float4*)(ap);
      float4 f1 = *(const float4*)(ap + 4);
      uint4 pk;
      pk.x = (unsigned)f2bf(f0.x) | ((unsigned)f2bf(f0.y) << 16);
      pk.y = (unsigned)f2bf(f0.z) | ((unsigned)f2bf(f0.w) << 16);
      pk.z = (unsigned)f2bf(f1.x) | ((unsigned)f2bf(f1.y) << 16);
      pk.w = (unsigned)f2bf(f1.z) | ((unsigned)f2bf(f1.w) << 16);
      *(uint4*)(lsA + srow * LDSS + sk) = pk;
    }
    *(uint4*)(lsB + srow * LDSS + sk) =
        *(const uint4*)(Wt + (size_t)(n0 + srow) * K + k0 + sk);
    __syncthreads();
    const short8 a = *(const short8*)(lsA + (w * 16 + fr) * LDSS + kk);
#pragma unroll
    for (int c = 0; c < 4; ++c) {
      const short8 b = *(const short8*)(lsB + (c * 16 + fr) * LDSS + kk);
      acc[c] = __builtin_amdgcn_mfma_f32_16x16x32_bf16(a, b, acc[c], 0, 0, 0);
    }
    __syncthreads();
  }

  const int fq = l >> 4;
#pragma unroll
  for (int c = 0; c < 4; ++c) {
#pragma unroll
    for (int r = 0; r < 4; ++r) {
      const int row = m0 + w * 16 + fq * 4 + r;
      const int col = n0 + c * 16 + fr;
      float v = acc[c][r];
      if (MODE == 0) {
        v += bias0[col];
        const int bb = (row >= LVN) ? 1 : 0;
        const int i = row - bb * LVN;
        const int lvl = (i >= 16384) + (i >= 20480) + (i >= 21504);
        const int stl = (lvl == 0) ? 0 : (lvl == 1) ? 16384 : (lvl == 2) ? 20480 : 21504;
        const int pst = (lvl == 0) ? 0 : (lvl == 1) ? 16900 : (lvl == 2) ? 21256 : 22412;
        const int lw = 7 - lvl;
        const int Wl = 128 >> lvl;
        const int loc = i - stl;
        const int y = loc >> lw;
        const int x = loc & (Wl - 1);
        const int pidx = pst + (y + 1) * (Wl + 2) + (x + 1);
        const int hh = col >> 5, d = col & 31;
        out_bf[(((size_t)(bb * HDN + hh) * PADCELLS + pidx) << 5) + d] = f2bf(v);
      } else if (MODE == 1) {
        const float bias = (col < 256) ? bias0[col] : bias1[col - 256];
        out_bf[(size_t)row * 384 + col] = f2bf(v + bias);
      } else {
        const size_t o = (size_t)row * 256 + col;
        out_f32[o] = v + bias0[col] + resid[o];
      }
    }
  }
}

// --- sampler: block = 64 queries x ONE (b,h) image; XCD-pinned by lid%8 ----
// wave = 16 queries x 4 lanes (8 dims each); inner loop identical to R4.
__global__ __launch_bounds__(256) void sampler_kernel(
    const unsigned short* __restrict__ vbf,      // padded [B,HD,PADCELLS,32]
    const unsigned short* __restrict__ offattn,  // [B*LQ,384] bf16
    const float* __restrict__ refpts,            // [B,LQ,4,2] f32
    unsigned short* __restrict__ msout) {        // [B*LQ,256] bf16
  const int lid = blockIdx.x;            // 0 .. 5439
  const int pair = lid & 7;              // image pair -> XCD (empirical %8)
  const int k = lid >> 3;                // 0 .. 679
  const int img = pair * 2 + (k & 1);    // 0 .. 15  (= bb*8 + h)
  const int qchunk = k >> 1;             // 0 .. 339
  const int h = img & 7;
  const int bb = img >> 3;

  const int t = threadIdx.x;
  const int lane = t & 63;
  const int qloc = qchunk * 64 + (t >> 6) * 16 + (lane >> 2);
  const int qi = bb * LQN + qloc;
  const int d0 = (lane & 3) * 8;

  const unsigned short* oa = offattn + (size_t)qi * 384;

  // ---- softmax over 16 logits for this (q,h); fold 1/sum in ----
  float lg[16];
  {
    const uint4 r0 = *(const uint4*)(oa + 256 + h * 16);
    const uint4 r1 = *(const uint4*)(oa + 256 + h * 16 + 8);
    const unsigned int ww[8] = {r0.x, r0.y, r0.z, r0.w, r1.x, r1.y, r1.z, r1.w};
#pragma unroll
    for (int j = 0; j < 8; ++j) {
      lg[2 * j] = bflo(ww[j]);
      lg[2 * j + 1] = bfhi(ww[j]);
    }
  }
  float mx = lg[0];
#pragma unroll
  for (int j = 1; j < 16; ++j) mx = fmaxf(mx, lg[j]);
  float ssum = 0.f;
#pragma unroll
  for (int j = 0; j < 16; ++j) {
    lg[j] = __expf(lg[j] - mx);
    ssum += lg[j];
  }
  const float inv = 1.f / ssum;
#pragma unroll
  for (int j = 0; j < 16; ++j) lg[j] *= inv;

  // lane-constant 32-bit element offset into padded vbf
  const unsigned int headbase =
      (unsigned int)img * (PADCELLS * DDIM) + (unsigned int)d0;

  f32x2 acc0 = (f32x2){0.f, 0.f}, acc1 = (f32x2){0.f, 0.f};
  f32x2 acc2 = (f32x2){0.f, 0.f}, acc3 = (f32x2){0.f, 0.f};

  const float4 refA = *(const float4*)(refpts + (size_t)qi * 8);
  const float4 refB = *(const float4*)(refpts + (size_t)qi * 8 + 4);
  const float rxs[4] = {refA.x, refA.z, refB.x, refB.z};
  const float rys[4] = {refA.y, refA.w, refB.y, refB.w};

#pragma unroll
  for (int lvl = 0; lvl < 4; ++lvl) {
    const int Wl = 128 >> lvl;
    const int W2 = Wl + 2;
    const int pst =
        (lvl == 0) ? 0 : (lvl == 1) ? 16900 : (lvl == 2) ? 21256 : 22412;
    const float fw = (float)Wl;
    const float rx = rxs[lvl], ry = rys[lvl];
    const uint4 ov = *(const uint4*)(oa + h * 32 + lvl * 8);
    const unsigned int op_[4] = {ov.x, ov.y, ov.z, ov.w};
#pragma unroll
    for (int p = 0; p < 4; ++p) {
      const float ox = bflo(op_[p]);
      const float oy = bfhi(op_[p]);
      const float xs = fmaf(rx, fw, ox) - 0.5f;
      const float ys = fmaf(ry, fw, oy) - 0.5f;
      const float x0f = floorf(xs), y0f = floorf(ys);
      const float lx = xs - x0f, ly = ys - y0f;
      const int x0 = (int)x0f, y0 = (int)y0f;
      const float aw = lg[lvl * 4 + p];
      const float wy1 = aw * ly, wy0 = aw - wy1;
      const float w01 = wy0 * lx, w00 = wy0 - w01;
      const float w11 = wy1 * lx, w10 = wy1 - w11;
      // clamp into padded coords (border cells are zero -> OOB contributes 0)
      const int xb0 = min(max(x0 + 1, 0), Wl + 1);
      const int xb1 = min(max(x0 + 2, 0), Wl + 1);
      const int yb0 = min(max(y0 + 1, 0), Wl + 1);
      const int yb1 = min(max(y0 + 2, 0), Wl + 1);
      const unsigned r0 = (unsigned)(pst + yb0 * W2);
      const unsigned r1 = (unsigned)(pst + yb1 * W2);
      const uint4 v00 = *(const uint4*)(vbf + headbase + ((r0 + xb0) << 5));
      const uint4 v01 = *(const uint4*)(vbf + headbase + ((r0 + xb1) << 5));
      const uint4 v10 = *(const uint4*)(vbf + headbase + ((r1 + xb0) << 5));
      const uint4 v11 = *(const uint4*)(vbf + headbase + ((r1 + xb1) << 5));

#define ACCUM(rv, wgt)                                 \
  {                                                    \
    f32x2 v_;                                          \
    v_.x = bflo(rv.x); v_.y = bfhi(rv.x);              \
    acc0 += v_ * (wgt);                                \
    v_.x = bflo(rv.y); v_.y = bfhi(rv.y);              \
    acc1 += v_ * (wgt);                                \
    v_.x = bflo(rv.z); v_.y = bfhi(rv.z);              \
    acc2 += v_ * (wgt);                                \
    v_.x = bflo(rv.w); v_.y = bfhi(rv.w);              \
    acc3 += v_ * (wgt);                                \
  }

      ACCUM(v00, w00)
      ACCUM(v01, w01)
      ACCUM(v10, w10)
      ACCUM(v11, w11)
#undef ACCUM
    }
  }

  uint4 outv;
  outv.x = (unsigned)f2bf(acc0.x) | ((unsigned)f2bf(acc0.y) << 16);
  outv.y = (unsigned)f2bf(acc1.x) | ((unsigned)f2bf(acc1.y) << 16);
  outv.z = (unsigned)f2bf(acc2.x) | ((unsigned)f2bf(acc2.y) << 16);
  outv.w = (unsigned)f2bf(acc3.x) | ((unsigned)f2bf(acc3.y) << 16);
  *(uint4*)(msout + (size_t)qi * 256 + h * 32 + d0) = outv;
}

// ---------------- launch ----------------------------------------------------
extern "C" void kernel_launch(void* const* d_in, const int* in_sizes, int n_in,
                              void* d_out, int out_size, void* d_ws,
                              size_t ws_size, hipStream_t stream) {
  const float* query = (const float*)d_in[0];
  const float* refpts = (const float*)d_in[1];
  const float* value = (const float*)d_in[2];
  const float* W_off = (const float*)d_in[5];
  const float* b_off = (const float*)d_in[6];
  const float* W_attn = (const float*)d_in[7];
  const float* b_attn = (const float*)d_in[8];
  const float* W_val = (const float*)d_in[9];
  const float* b_val = (const float*)d_in[10];
  const float* W_out = (const float*)d_in[11];
  const float* b_out = (const float*)d_in[12];
  float* out = (float*)d_out;

  char* ws = (char*)d_ws;
  unsigned short* wtval = (unsigned short*)(ws);                 // 131072 B
  unsigned short* wtoa = (unsigned short*)(ws + 131072);         // 196608 B
  unsigned short* wtout = (unsigned short*)(ws + 327680);        // 131072 B
  unsigned short* vbf = (unsigned short*)(ws + 458752);          // 23281664 B
  unsigned short* offattn = (unsigned short*)(ws + 23740416);    // 33423360 B
  unsigned short* msout = (unsigned short*)(ws + 57163776);      // 22282240 B

  // 2*8*PADCELLS*32 shorts = 1455104 uint4
  zero_kernel<<<5684, 256, 0, stream>>>((uint4*)vbf);
  prep_kernel<<<384, 256, 0, stream>>>(W_val, W_off, W_attn, W_out, wtval, wtoa,
                                       wtout);
  gemm_kernel<0><<<dim3(680, 4), 256, 0, stream>>>(
      value, nullptr, wtval, b_val, nullptr, nullptr, vbf, nullptr);
  gemm_kernel<1><<<dim3(680, 6), 256, 0, stream>>>(
      query, nullptr, wtoa, b_off, b_attn, nullptr, offattn, nullptr);
  sampler_kernel<<<5440, 256, 0, stream>>>(vbf, offattn, refpts, msout);
  gemm_kernel<2><<<dim3(680, 4), 256, 0, stream>>>(
      nullptr, msout, wtout, b_out, nullptr, query, nullptr, out);
}